// Round 2
// baseline (216.366 us; speedup 1.0000x reference)
//
#include <hip/hip_runtime.h>
#include <hip/hip_bf16.h>
#include <stdint.h>

#define LOG2E 1.4426950408889634f

typedef __bf16 v8bf __attribute__((ext_vector_type(8)));
typedef float v16f __attribute__((ext_vector_type(16)));

#if __has_builtin(__builtin_amdgcn_exp2f)
#define EXP2(x) __builtin_amdgcn_exp2f(x)
#else
#define EXP2(x) exp2f(x)
#endif

static constexpr int B = 4, N = 2048, FIN = 128, H = 4, DK = 32;
static constexpr int JS = 4;            // j-split for occupancy
static constexpr int IT = N / 32;       // 64 i-tiles
static constexpr int NSTEP = (N / JS) / 16;  // 32 K-steps per wave

// ---------------- kernel 0: transpose W[h][i][d] -> wt[h][d][i] ----------------
__global__ void k_wt(const float* __restrict__ W, float* __restrict__ wt) {
  int idx = blockIdx.x * 256 + threadIdx.x;
  if (idx < H * DK * FIN) {
    int h = idx >> 12;          // DK*FIN = 4096
    int r = idx & 4095;
    int d = r >> 7;
    int i = r & 127;
    wt[idx] = W[h * FIN * DK + i * DK + d];
  }
}

// ---------------- kernel 1: h projection + el/er (scaled by log2e) ----------------
// h_t[b][h][d][n] bf16 (transposed for MFMA B-operand loads), el/er[b][h][n] f32
__global__ __launch_bounds__(128) void k_hproj(
    const float* __restrict__ x, const float* __restrict__ a,
    const float* __restrict__ wt, unsigned short* __restrict__ h_t,
    float* __restrict__ el, float* __restrict__ er) {
  int b = blockIdx.x >> 11;          // N = 2048
  int n = blockIdx.x & (N - 1);
  int t = threadIdx.x;
  int head = t >> 5, d = t & 31;
  const float4* xp = (const float4*)(x + (b * N + n) * FIN);          // broadcast across lanes
  const float4* wp = (const float4*)(wt + (head * DK + d) * FIN);     // per-lane row, L1-resident
  float acc = 0.f;
#pragma unroll 8
  for (int i = 0; i < FIN / 4; ++i) {
    float4 xv = xp[i], wv = wp[i];
    acc = fmaf(xv.x, wv.x, acc);
    acc = fmaf(xv.y, wv.y, acc);
    acc = fmaf(xv.z, wv.z, acc);
    acc = fmaf(xv.w, wv.w, acc);
  }
  // round-to-nearest-ish bf16 (add half ulp then truncate)
  unsigned int ub = (__builtin_bit_cast(unsigned int, acc) + 0x8000u) >> 16;
  h_t[((b * H + head) * DK + d) * N + n] = (unsigned short)ub;
  // el/er reduction over d within each 32-lane half-wave; fold log2e in here
  float al = a[head * 2 * DK + d] * LOG2E;
  float ar = a[head * 2 * DK + DK + d] * LOG2E;
  float cl = acc * al;
  float cr = acc * ar;
  for (int o = 16; o; o >>= 1) {
    cl += __shfl_down(cl, o, 32);
    cr += __shfl_down(cr, o, 32);
  }
  if (d == 0) {
    el[(b * H + head) * N + n] = cl;
    er[(b * H + head) * N + n] = cr;
  }
}

// ---------------- kernel 2: fused masked-softmax-numerator via MFMA ----------------
// grid: B * IT * JS blocks, 256 threads (wave w = head w). Each wave computes a
// partial 32(i) x 32(d) numerator tile over j in [js*512, js*512+512) + row sums.
__global__ __launch_bounds__(256, 4) void k_attn(
    const int* __restrict__ adj, const unsigned short* __restrict__ h_t,
    const float* __restrict__ el, const float* __restrict__ er,
    float* __restrict__ pnum, float* __restrict__ pl) {
  int blk = blockIdx.x;
  int b = blk >> 8;                 // IT*JS = 256
  int rem = blk & 255;
  int it = rem >> 2, js = rem & 3;
  int tid = threadIdx.x;
  int head = tid >> 6, lane = tid & 63;
  int lrow = lane & 31;             // A-operand row (i) == C/B column (d)
  int kh = lane >> 5;               // which 8-wide k half
  int ig = it * 32 + lrow;
  int bh = b * H + head;

  float eli = el[bh * N + ig];
  const int* arow = adj + (b * N + ig) * N + js * (N / JS) + kh * 8;
  const float* erp = er + bh * N + js * (N / JS) + kh * 8;
  const unsigned short* hp = h_t + (bh * DK + lrow) * N + js * (N / JS) + kh * 8;

  v16f acc;
#pragma unroll
  for (int i = 0; i < 16; ++i) acc[i] = 0.f;
  float lsum = 0.f;

  int4 A0a, A0b, A1a, A1b, Hb0, Hb1;
  float4 E0a, E0b, E1a, E1b;

#define LOADS(Aa, Ab, Ea, Eb, Hb, s)                                        \
  do {                                                                      \
    int o_ = (s) * 16;                                                      \
    Aa = *(const int4*)(arow + o_);                                         \
    Ab = *(const int4*)(arow + o_ + 4);                                     \
    Ea = *(const float4*)(erp + o_);                                        \
    Eb = *(const float4*)(erp + o_ + 4);                                    \
    Hb = *(const int4*)(hp + o_);                                           \
  } while (0)

  auto step = [&](int4 aa, int4 ab, float4 ea, float4 eb, int4 hb) {
    int ad[8] = {aa.x, aa.y, aa.z, aa.w, ab.x, ab.y, ab.z, ab.w};
    float ev[8] = {ea.x, ea.y, ea.z, ea.w, eb.x, eb.y, eb.z, eb.w};
    unsigned int ubits[8];
#pragma unroll
    for (int k = 0; k < 8; ++k) {
      float tt = eli + ev[k];
      tt = fmaxf(tt, 0.2f * tt);          // leaky relu (scale-invariant, log2e pre-folded)
      float pv = EXP2(tt);
      pv = ad[k] ? pv : 0.f;              // adjacency mask
      unsigned int ub = __builtin_bit_cast(unsigned int, pv);
      ubits[k] = ub;
      // accumulate the *truncated* value so numerator/denominator stay consistent
      lsum += __builtin_bit_cast(float, ub & 0xFFFF0000u);
    }
    unsigned int u0 = __builtin_amdgcn_perm(ubits[1], ubits[0], 0x07060302u);
    unsigned int u1 = __builtin_amdgcn_perm(ubits[3], ubits[2], 0x07060302u);
    unsigned int u2 = __builtin_amdgcn_perm(ubits[5], ubits[4], 0x07060302u);
    unsigned int u3 = __builtin_amdgcn_perm(ubits[7], ubits[6], 0x07060302u);
    uint4 au = {u0, u1, u2, u3};
    v8bf av = __builtin_bit_cast(v8bf, au);
    v8bf hv = __builtin_bit_cast(v8bf, hb);
    acc = __builtin_amdgcn_mfma_f32_32x32x16_bf16(av, hv, acc, 0, 0, 0);
  };

  LOADS(A0a, A0b, E0a, E0b, Hb0, 0);
  LOADS(A1a, A1b, E1a, E1b, Hb1, 1);
  for (int s = 0; s < NSTEP; s += 2) {
    int4 aa = A0a, ab = A0b, hb = Hb0;
    float4 ea = E0a, eb = E0b;
    if (s + 2 < NSTEP) LOADS(A0a, A0b, E0a, E0b, Hb0, s + 2);
    step(aa, ab, ea, eb, hb);
    aa = A1a; ab = A1b; hb = Hb1; ea = E1a; eb = E1b;
    if (s + 3 < NSTEP) LOADS(A1a, A1b, E1a, E1b, Hb1, s + 3);
    step(aa, ab, ea, eb, hb);
  }
#undef LOADS

  // row sum: lanes l and l+32 each covered half the j's of row (l&31)
  lsum += __shfl_xor(lsum, 32);
  int tile = (bh * IT + it) * JS + js;
  if (lane < 32) pl[tile * 32 + lane] = lsum;
  float* pn = pnum + tile * 1024;
#pragma unroll
  for (int r = 0; r < 16; ++r) {
    int rowl = (r & 3) + 8 * (r >> 2) + 4 * kh;   // C/D row mapping (32x32 bf16, m74/m101)
    pn[rowl * 32 + lrow] = acc[r];
  }
}

// ---------------- kernel 3: combine partials, divide, write out ----------------
__global__ __launch_bounds__(256) void k_comb(
    const float* __restrict__ pnum, const float* __restrict__ pl,
    float* __restrict__ out) {
  int idx = blockIdx.x * 256 + threadIdx.x;   // ((b*H+h)*N + i)*DK + d
  int d = idx & 31;
  int i = (idx >> 5) & (N - 1);
  int bh = idx >> 16;                         // N*DK = 65536
  int it = i >> 5, row = i & 31;
  int tb = (bh * IT + it) * JS;
  float num = 0.f, l = 0.f;
#pragma unroll
  for (int js = 0; js < JS; ++js) {
    num += pnum[(tb + js) * 1024 + row * 32 + d];
    l += pl[(tb + js) * 32 + row];
  }
  out[idx] = num / l;
}

extern "C" void kernel_launch(void* const* d_in, const int* in_sizes, int n_in,
                              void* d_out, int out_size, void* d_ws, size_t ws_size,
                              hipStream_t stream) {
  const float* x = (const float*)d_in[0];
  const int* adj = (const int*)d_in[1];
  const float* W = (const float*)d_in[2];
  const float* a = (const float*)d_in[3];
  float* out = (float*)d_out;
  char* ws = (char*)d_ws;
  // workspace layout (~19.7 MB total)
  unsigned short* h_t = (unsigned short*)(ws);            // 2 MB bf16 [B][H][DK][N]
  float* el = (float*)(ws + 0x200000);                    // 128 KB
  float* er = (float*)(ws + 0x220000);                    // 128 KB
  float* pl = (float*)(ws + 0x240000);                    // 512 KB partial row sums
  float* wt = (float*)(ws + 0x2C0000);                    // 64 KB W transposed
  float* pnum = (float*)(ws + 0x2D0000);                  // 16 MB partial numerators

  hipLaunchKernelGGL(k_wt, dim3(64), dim3(256), 0, stream, W, wt);
  hipLaunchKernelGGL(k_hproj, dim3(B * N), dim3(128), 0, stream, x, a, wt, h_t, el, er);
  hipLaunchKernelGGL(k_attn, dim3(B * IT * JS), dim3(256), 0, stream, adj, h_t, el, er, pnum, pl);
  hipLaunchKernelGGL(k_comb, dim3((B * N * H * DK) / 256), dim3(256), 0, stream, pnum, pl, out);
}

// Round 3
// 166.319 us; speedup vs baseline: 1.3009x; 1.3009x over previous
//
#include <hip/hip_runtime.h>
#include <stdint.h>

#define LOG2E 1.4426950408889634f

typedef __bf16 v8bf __attribute__((ext_vector_type(8)));
typedef float v16f __attribute__((ext_vector_type(16)));

static constexpr int B = 4, N = 2048, FIN = 128, H = 4, DK = 32;
static constexpr int IT = N / 32;   // 64 i-tiles

__device__ __forceinline__ float exp2_fast(float x) {
#if __has_builtin(__builtin_amdgcn_exp2f)
  return __builtin_amdgcn_exp2f(x);
#else
  float r;
  asm("v_exp_f32 %0, %1" : "=v"(r) : "v"(x));
  return r;
#endif
}

__device__ __forceinline__ unsigned int bf16_rne(float f) {
  unsigned int u = __builtin_bit_cast(unsigned int, f);
  u += 0x7FFFu + ((u >> 16) & 1u);
  return u >> 16;
}

// ---------------- kernel 0: cast x->bf16 (same layout) + wtb[h][d][f] bf16 ----------------
__global__ __launch_bounds__(256) void k_prep(const float* __restrict__ x,
                                              const float* __restrict__ W,
                                              unsigned short* __restrict__ xb,
                                              unsigned short* __restrict__ wtb) {
  int idx = blockIdx.x * 256 + threadIdx.x;
  constexpr int TX = B * N * FIN;          // 1048576
  if (idx < TX) {
    xb[idx] = (unsigned short)bf16_rne(x[idx]);
  } else {
    int j = idx - TX;                      // < H*DK*FIN = 16384
    int h = j >> 12, r = j & 4095, d = r >> 7, f = r & 127;
    wtb[j] = (unsigned short)bf16_rne(W[(h * FIN + f) * DK + d]);
  }
}

// ---------------- kernel 1: h projection via MFMA; writes h_t[bh][d][n] + el/er ----------------
// grid B*IT blocks x 256 threads; wave = head. D tile: rows=d(32), cols=n(32).
__global__ __launch_bounds__(256) void k_hproj(const unsigned short* __restrict__ xb,
                                               const unsigned short* __restrict__ wtb,
                                               const float* __restrict__ a,
                                               unsigned short* __restrict__ h_t,
                                               float* __restrict__ el,
                                               float* __restrict__ er) {
  int blk = blockIdx.x;
  int b = blk >> 6, it = blk & 63;
  int tid = threadIdx.x;
  int head = tid >> 6, lane = tid & 63;
  int lrow = lane & 31, kh = lane >> 5;
  int bh = b * H + head;
  int n = it * 32 + lrow;
  const unsigned short* xp = xb + (b * N + n) * FIN + kh * 8;       // B row = n, k = f
  const unsigned short* wp = wtb + (head * DK + lrow) * FIN + kh * 8; // A row = d, k = f
  v16f acc = {};
#pragma unroll
  for (int s = 0; s < FIN / 16; ++s) {
    v8bf av = __builtin_bit_cast(v8bf, *(const int4*)(wp + s * 16));
    v8bf bv = __builtin_bit_cast(v8bf, *(const int4*)(xp + s * 16));
    acc = __builtin_amdgcn_mfma_f32_32x32x16_bf16(av, bv, acc, 0, 0, 0);
  }
  float pel = 0.f, per = 0.f;
#pragma unroll
  for (int r = 0; r < 16; ++r) {
    int d = (r & 3) + 8 * (r >> 2) + 4 * kh;   // C/D row mapping (32x32 bf16)
    float hv = acc[r];
    h_t[(bh * DK + d) * N + n] = (unsigned short)bf16_rne(hv);
    pel = fmaf(hv, a[head * 2 * DK + d], pel);
    per = fmaf(hv, a[head * 2 * DK + DK + d], per);
  }
  pel += __shfl_xor(pel, 32);
  per += __shfl_xor(per, 32);
  if (kh == 0) {
    el[bh * N + n] = pel * LOG2E;
    er[bh * N + n] = per * LOG2E;
  }
}

// ---------------- kernel 2: fused masked-softmax-numerator via MFMA ----------------
template <int JS>
__global__ __launch_bounds__(256, 8) void k_attn(const int* __restrict__ adj,
                                                 const unsigned short* __restrict__ h_t,
                                                 const float* __restrict__ el,
                                                 const float* __restrict__ er,
                                                 float* __restrict__ pnum,
                                                 float* __restrict__ pl) {
  constexpr int NSTEP = (N / JS) / 16;
  int blk = blockIdx.x;
  int b = blk / (IT * JS);
  int rem = blk % (IT * JS);
  int it = rem / JS, js = rem % JS;
  int tid = threadIdx.x;
  int head = tid >> 6, lane = tid & 63;
  int lrow = lane & 31, kh = lane >> 5;
  int ig = it * 32 + lrow;
  int bh = b * H + head;
  float eli = el[bh * N + ig];
  int j0 = js * (N / JS) + kh * 8;
  const int* arow = adj + (size_t)(b * N + ig) * N + j0;
  const float* erp = er + bh * N + j0;
  const unsigned short* hp = h_t + (size_t)(bh * DK + lrow) * N + j0;

  v16f acc = {};
  float lsum0 = 0.f, lsum1 = 0.f;

  int4 Aa = *(const int4*)(arow);
  int4 Ab = *(const int4*)(arow + 4);
  float4 Ea = *(const float4*)(erp);
  float4 Eb = *(const float4*)(erp + 4);
  int4 Hb = *(const int4*)(hp);

  for (int s = 0; s < NSTEP; ++s) {
    int4 aa = Aa, ab = Ab, hb = Hb;
    float4 ea = Ea, eb = Eb;
    if (s + 1 < NSTEP) {
      int o = (s + 1) * 16;
      Aa = *(const int4*)(arow + o);
      Ab = *(const int4*)(arow + o + 4);
      Ea = *(const float4*)(erp + o);
      Eb = *(const float4*)(erp + o + 4);
      Hb = *(const int4*)(hp + o);
    }
    int ad[8] = {aa.x, aa.y, aa.z, aa.w, ab.x, ab.y, ab.z, ab.w};
    float ev[8] = {ea.x, ea.y, ea.z, ea.w, eb.x, eb.y, eb.z, eb.w};
    unsigned int ub[8];
#pragma unroll
    for (int k = 0; k < 8; ++k) {
      float tt = eli + ev[k];
      tt = fmaxf(tt, 0.2f * tt);            // leaky relu (log2e pre-folded into el/er)
      float pv = exp2_fast(tt);
      pv = ad[k] ? pv : 0.f;                // adjacency mask
      unsigned int u = __builtin_bit_cast(unsigned int, pv) & 0xFFFF0000u;
      ub[k] = u;
      // sum the truncated bf16 value so numerator/denominator stay consistent
      if (k & 1) lsum1 += __builtin_bit_cast(float, u);
      else       lsum0 += __builtin_bit_cast(float, u);
    }
    unsigned int u0 = __builtin_amdgcn_perm(ub[1], ub[0], 0x07060302u);
    unsigned int u1 = __builtin_amdgcn_perm(ub[3], ub[2], 0x07060302u);
    unsigned int u2 = __builtin_amdgcn_perm(ub[5], ub[4], 0x07060302u);
    unsigned int u3 = __builtin_amdgcn_perm(ub[7], ub[6], 0x07060302u);
    uint4 au = {u0, u1, u2, u3};
    v8bf av = __builtin_bit_cast(v8bf, au);
    v8bf hv = __builtin_bit_cast(v8bf, hb);
    acc = __builtin_amdgcn_mfma_f32_32x32x16_bf16(av, hv, acc, 0, 0, 0);
  }

  float lsum = lsum0 + lsum1;
  lsum += __shfl_xor(lsum, 32);
  int tile = (bh * IT + it) * JS + js;
  if (lane < 32) pl[tile * 32 + lane] = lsum;
  float* pn = pnum + (size_t)tile * 1024;
#pragma unroll
  for (int r = 0; r < 16; ++r) {
    int rowl = (r & 3) + 8 * (r >> 2) + 4 * kh;   // i-row within tile
    pn[rowl * 32 + lrow] = acc[r];
  }
}

// ---------------- kernel 3: combine partials, divide, write out ----------------
template <int JS>
__global__ __launch_bounds__(256) void k_comb(const float* __restrict__ pnum,
                                              const float* __restrict__ pl,
                                              float* __restrict__ out) {
  int idx = blockIdx.x * 256 + threadIdx.x;   // ((b*H+h)*N + i)*DK + d
  int d = idx & 31;
  int i = (idx >> 5) & (N - 1);
  int bh = idx >> 16;                         // N*DK = 65536
  int it = i >> 5, row = i & 31;
  int tb = (bh * IT + it) * JS;
  float num = 0.f, l = 0.f;
#pragma unroll
  for (int js = 0; js < JS; ++js) {
    num += pnum[(size_t)(tb + js) * 1024 + row * 32 + d];
    l += pl[(tb + js) * 32 + row];
  }
  out[idx] = num / l;
}

extern "C" void kernel_launch(void* const* d_in, const int* in_sizes, int n_in,
                              void* d_out, int out_size, void* d_ws, size_t ws_size,
                              hipStream_t stream) {
  const float* x = (const float*)d_in[0];
  const int* adj = (const int*)d_in[1];
  const float* W = (const float*)d_in[2];
  const float* a = (const float*)d_in[3];
  float* out = (float*)d_out;
  char* ws = (char*)d_ws;

  unsigned short* h_t = (unsigned short*)(ws);             // 2 MB  [B][H][DK][N]
  float* el = (float*)(ws + 0x200000);                     // 128 KB
  float* er = (float*)(ws + 0x220000);                     // 128 KB
  float* pl = (float*)(ws + 0x240000);                     // up to 1 MB
  unsigned short* wtb = (unsigned short*)(ws + 0x340000);  // 32 KB [H][DK][FIN]
  float* pnum = (float*)(ws + 0x360000);                   // 16.8 / 33.6 MB

  size_t pnum8 = (size_t)B * H * IT * 8 * 1024 * 4;        // 33.6 MB
  bool use8 = ws_size >= 0x360000 + pnum8;
  size_t pnum_sz = use8 ? pnum8 : pnum8 / 2;
  // xb (2 MB) aliased into the tail of pnum: written by k_prep, read by k_hproj,
  // clobbered only later by k_attn.
  unsigned short* xb = (unsigned short*)(ws + 0x360000 + pnum_sz - (size_t)B * N * FIN * 2);

  hipLaunchKernelGGL(k_prep, dim3((B * N * FIN + H * DK * FIN) / 256), dim3(256), 0, stream,
                     x, W, xb, wtb);
  hipLaunchKernelGGL(k_hproj, dim3(B * IT), dim3(256), 0, stream, xb, wtb, a, h_t, el, er);
  if (use8) {
    hipLaunchKernelGGL((k_attn<8>), dim3(B * IT * 8), dim3(256), 0, stream,
                       adj, h_t, el, er, pnum, pl);
    hipLaunchKernelGGL((k_comb<8>), dim3(B * N * H * DK / 256), dim3(256), 0, stream,
                       pnum, pl, out);
  } else {
    hipLaunchKernelGGL((k_attn<4>), dim3(B * IT * 4), dim3(256), 0, stream,
                       adj, h_t, el, er, pnum, pl);
    hipLaunchKernelGGL((k_comb<4>), dim3(B * N * H * DK / 256), dim3(256), 0, stream,
                       pnum, pl, out);
  }
}

// Round 4
// 146.479 us; speedup vs baseline: 1.4771x; 1.1354x over previous
//
#include <hip/hip_runtime.h>
#include <stdint.h>

#define LOG2E 1.4426950408889634f

typedef __bf16 v8bf __attribute__((ext_vector_type(8)));
typedef float v16f __attribute__((ext_vector_type(16)));

static constexpr int B = 4, N = 2048, FIN = 128, H = 4, DK = 32;
static constexpr int IT = N / 32;   // 64 i-tiles

__device__ __forceinline__ float exp2_fast(float x) {
#if __has_builtin(__builtin_amdgcn_exp2f)
  return __builtin_amdgcn_exp2f(x);
#else
  float r;
  asm("v_exp_f32 %0, %1" : "=v"(r) : "v"(x));
  return r;
#endif
}

__device__ __forceinline__ unsigned int bf16_rne(float f) {
  unsigned int u = __builtin_bit_cast(unsigned int, f);
  u += 0x7FFFu + ((u >> 16) & 1u);
  return u >> 16;
}

// ---------------- kernel 0: cast x->bf16 + wtb[h][d][f] bf16 ----------------
__global__ __launch_bounds__(256) void k_prep(const float* __restrict__ x,
                                              const float* __restrict__ W,
                                              unsigned short* __restrict__ xb,
                                              unsigned short* __restrict__ wtb) {
  int idx = blockIdx.x * 256 + threadIdx.x;
  constexpr int TX = B * N * FIN;          // 1048576
  if (idx < TX) {
    xb[idx] = (unsigned short)bf16_rne(x[idx]);
  } else {
    int j = idx - TX;                      // < H*DK*FIN = 16384
    int h = j >> 12, r = j & 4095, d = r >> 7, f = r & 127;
    wtb[j] = (unsigned short)bf16_rne(W[(h * FIN + f) * DK + d]);
  }
}

// ---------------- kernel 1: bit-pack adjacency: adjb[b][i][j/32] ----------------
// wave handles 256 consecutive ints (one row never crossed: 2048 % 256 == 0)
__global__ __launch_bounds__(256) void k_pack(const int* __restrict__ adj,
                                              unsigned int* __restrict__ adjb) {
  int wid = (blockIdx.x * 256 + threadIdx.x) >> 6;
  int lane = threadIdx.x & 63;
  const int* p = adj + (size_t)wid * 256 + lane;
  unsigned long long m0 = __ballot(p[0] != 0);
  unsigned long long m1 = __ballot(p[64] != 0);
  unsigned long long m2 = __ballot(p[128] != 0);
  unsigned long long m3 = __ballot(p[192] != 0);
  if (lane == 0) {
    uint4 v0 = {(unsigned)m0, (unsigned)(m0 >> 32), (unsigned)m1, (unsigned)(m1 >> 32)};
    uint4 v1 = {(unsigned)m2, (unsigned)(m2 >> 32), (unsigned)m3, (unsigned)(m3 >> 32)};
    uint4* dst = (uint4*)(adjb + (size_t)wid * 8);
    dst[0] = v0;
    dst[1] = v1;
  }
}

// ---------------- kernel 2: h projection via MFMA; h_t[bh][d][n] + el/er ----------------
__global__ __launch_bounds__(256) void k_hproj(const unsigned short* __restrict__ xb,
                                               const unsigned short* __restrict__ wtb,
                                               const float* __restrict__ a,
                                               unsigned short* __restrict__ h_t,
                                               float* __restrict__ el,
                                               float* __restrict__ er) {
  int blk = blockIdx.x;
  int b = blk >> 6, it = blk & 63;
  int tid = threadIdx.x;
  int head = tid >> 6, lane = tid & 63;
  int lrow = lane & 31, kh = lane >> 5;
  int bh = b * H + head;
  int n = it * 32 + lrow;
  const unsigned short* xp = xb + (b * N + n) * FIN + kh * 8;
  const unsigned short* wp = wtb + (head * DK + lrow) * FIN + kh * 8;
  v16f acc = {};
#pragma unroll
  for (int s = 0; s < FIN / 16; ++s) {
    v8bf av = __builtin_bit_cast(v8bf, *(const int4*)(wp + s * 16));
    v8bf bv = __builtin_bit_cast(v8bf, *(const int4*)(xp + s * 16));
    acc = __builtin_amdgcn_mfma_f32_32x32x16_bf16(av, bv, acc, 0, 0, 0);
  }
  float pel = 0.f, per = 0.f;
#pragma unroll
  for (int r = 0; r < 16; ++r) {
    int d = (r & 3) + 8 * (r >> 2) + 4 * kh;   // C/D row mapping (32x32 bf16)
    float hv = acc[r];
    h_t[(bh * DK + d) * N + n] = (unsigned short)bf16_rne(hv);
    pel = fmaf(hv, a[head * 2 * DK + d], pel);
    per = fmaf(hv, a[head * 2 * DK + DK + d], per);
  }
  pel += __shfl_xor(pel, 32);
  per += __shfl_xor(per, 32);
  if (kh == 0) {
    el[bh * N + n] = pel * LOG2E;
    er[bh * N + n] = per * LOG2E;
  }
}

// ---------------- kernel 3: fused attention, in-block js-reduction, final out ----------------
// block = (b, it): 1024 threads = 16 waves = (jq 0..3) x (head 0..3)
__global__ __launch_bounds__(1024, 4) void k_attn(const unsigned int* __restrict__ adjb,
                                                  const unsigned short* __restrict__ h_t,
                                                  const float* __restrict__ el,
                                                  const float* __restrict__ er,
                                                  float* __restrict__ out) {
  __shared__ float part[H][1024];   // [head][i*32+d] accumulated across jq
  __shared__ float lsh[H][32];      // [head][i]
  int blk = blockIdx.x;
  int b = blk >> 6, it = blk & 63;
  int tid = threadIdx.x;
  int wave = tid >> 6;
  int head = wave & 3, jq = wave >> 2;
  int lane = tid & 63, lrow = lane & 31, kh = lane >> 5;
  int ig = it * 32 + lrow, bh = b * H + head;

  // zero the reduction buffers
  part[tid >> 8][tid & 255] = 0.f;
  part[tid >> 8][256 + (tid & 255)] = 0.f;
  part[tid >> 8][512 + (tid & 255)] = 0.f;
  part[tid >> 8][768 + (tid & 255)] = 0.f;
  if (tid < H * 32) lsh[tid >> 5][tid & 31] = 0.f;

  float eli = el[bh * N + ig];
  int j0 = jq * 512 + kh * 8;
  const float* erp = er + bh * N + j0;
  const unsigned short* hp = h_t + (size_t)(bh * DK + lrow) * N + j0;

  // preload this lane's adjacency bits for its whole j-quarter (512 bits)
  const uint4* abp = (const uint4*)(adjb + (size_t)(b * N + ig) * 64 + jq * 16);
  uint4 ab0 = abp[0], ab1 = abp[1], ab2 = abp[2], ab3 = abp[3];
  unsigned adw[16] = {ab0.x, ab0.y, ab0.z, ab0.w, ab1.x, ab1.y, ab1.z, ab1.w,
                      ab2.x, ab2.y, ab2.z, ab2.w, ab3.x, ab3.y, ab3.z, ab3.w};
  int shkh = kh * 8;

  __syncthreads();   // part/lsh zeroing visible before atomics

  v16f acc = {};
  float lsum = 0.f;
  float4 Ea = *(const float4*)erp;
  float4 Eb = *(const float4*)(erp + 4);
  int4 Hb = *(const int4*)hp;
#pragma unroll
  for (int s = 0; s < 32; ++s) {
    float4 ea = Ea, eb = Eb;
    int4 hb = Hb;
    if (s + 1 < 32) {
      int o = (s + 1) * 16;
      Ea = *(const float4*)(erp + o);
      Eb = *(const float4*)(erp + o + 4);
      Hb = *(const int4*)(hp + o);
    }
    unsigned mb = (adw[s >> 1] >> (((s & 1) * 16) + shkh)) & 0xFFu;
    float ev[8] = {ea.x, ea.y, ea.z, ea.w, eb.x, eb.y, eb.z, eb.w};
    unsigned ub[8];
#pragma unroll
    for (int k = 0; k < 8; ++k) {
      float tt = eli + ev[k];
      tt = fmaxf(tt, 0.2f * tt);            // leaky relu (log2e pre-folded)
      float pv = exp2_fast(tt);
      unsigned u = __builtin_bit_cast(unsigned, pv) & 0xFFFF0000u;
      u = (mb & (1u << k)) ? u : 0u;        // adjacency bit mask
      ub[k] = u;
      lsum += __builtin_bit_cast(float, u); // truncated value: num/den consistent
    }
    unsigned u0 = __builtin_amdgcn_perm(ub[1], ub[0], 0x07060302u);
    unsigned u1 = __builtin_amdgcn_perm(ub[3], ub[2], 0x07060302u);
    unsigned u2 = __builtin_amdgcn_perm(ub[5], ub[4], 0x07060302u);
    unsigned u3 = __builtin_amdgcn_perm(ub[7], ub[6], 0x07060302u);
    uint4 au = {u0, u1, u2, u3};
    v8bf av = __builtin_bit_cast(v8bf, au);
    v8bf hv = __builtin_bit_cast(v8bf, hb);
    acc = __builtin_amdgcn_mfma_f32_32x32x16_bf16(av, hv, acc, 0, 0, 0);
  }

  lsum += __shfl_xor(lsum, 32);
  if (lane < 32) atomicAdd(&lsh[head][lane], lsum);
#pragma unroll
  for (int r = 0; r < 16; ++r) {
    int rowl = (r & 3) + 8 * (r >> 2) + 4 * kh;   // i-row within tile
    atomicAdd(&part[head][rowl * 32 + lrow], acc[r]);
  }
  __syncthreads();

  // 4096 outputs / 1024 threads = one float4 each, coalesced
  int e = tid * 4;
  int rh = e >> 10;
  int ri = (e >> 5) & 31;
  int rd = e & 31;
  float4 s4 = *(const float4*)&part[rh][ri * 32 + rd];
  float inv = 1.0f / lsh[rh][ri];
  float4 o;
  o.x = s4.x * inv;
  o.y = s4.y * inv;
  o.z = s4.z * inv;
  o.w = s4.w * inv;
  *(float4*)&out[(size_t)((b * H + rh) * N + it * 32 + ri) * DK + rd] = o;
}

extern "C" void kernel_launch(void* const* d_in, const int* in_sizes, int n_in,
                              void* d_out, int out_size, void* d_ws, size_t ws_size,
                              hipStream_t stream) {
  const float* x = (const float*)d_in[0];
  const int* adj = (const int*)d_in[1];
  const float* W = (const float*)d_in[2];
  const float* a = (const float*)d_in[3];
  float* out = (float*)d_out;
  char* ws = (char*)d_ws;

  unsigned short* h_t = (unsigned short*)(ws);             // 2 MB  [B][H][DK][N]
  float* el = (float*)(ws + 0x200000);                     // 128 KB
  float* er = (float*)(ws + 0x220000);                     // 128 KB
  unsigned short* wtb = (unsigned short*)(ws + 0x240000);  // 32 KB
  unsigned int* adjb = (unsigned int*)(ws + 0x250000);     // 2 MB bitmask
  unsigned short* xb = (unsigned short*)(ws + 0x450000);   // 2 MB
  // total 6.3 MB — well under the workspace that held 20+ MB before

  hipLaunchKernelGGL(k_pack, dim3(B * N * N / 256 / 4), dim3(256), 0, stream, adj, adjb);
  hipLaunchKernelGGL(k_prep, dim3((B * N * FIN + H * DK * FIN) / 256), dim3(256), 0, stream,
                     x, W, xb, wtb);
  hipLaunchKernelGGL(k_hproj, dim3(B * IT), dim3(256), 0, stream, xb, wtb, a, h_t, el, er);
  hipLaunchKernelGGL(k_attn, dim3(B * IT), dim3(1024), 0, stream, adjb, h_t, el, er, out);
}